// Round 5
// baseline (325.532 us; speedup 1.0000x reference)
//
#include <hip/hip_runtime.h>
#include <hip/hip_bf16.h>

// SRU cell, fp32 in / fp32 out (internal bf16 MFMA GEMM).
// L=1024, B=32, d=512. M=32768, K=512, N=1536.
// ws: Wt (bf16 [N][K], 1.5MB) | u (bf16 [M][N], 96MB)

typedef __attribute__((ext_vector_type(8))) __bf16 bf16x8;
typedef __attribute__((ext_vector_type(4))) __bf16 bf16x4;
typedef __attribute__((ext_vector_type(4))) float floatx4;

#define LOG2E 1.4426950408889634f

// ---- convert + transpose weight: W[K][N] fp32 -> Wt[N][K] bf16 ---------------
__global__ __launch_bounds__(256) void cvt_w(const float* __restrict__ w,
                                             __bf16* __restrict__ wt) {
  int idx = blockIdx.x * 256 + threadIdx.x;  // 0..786431 = n*512+k
  int n = idx >> 9, k = idx & 511;
  wt[idx] = (__bf16)w[(size_t)k * 1536 + n];
}

// ---- GEMM: A-resident-LDS, n-loop inside -------------------------------------
// 512 blocks, m-tile 64. A (64x512 fp32) read ONCE -> bf16 LDS [m][swizzled 8k-
// chunk] (64KB). Loop 12 n-tiles x 16 k-iters (BK=32) with 2-deep B LDS ring
// (2x8KB) via global_load_lds (B is L2-resident, 1.5MB). LDS total 80KiB ->
// exactly 2 blocks/CU; sibling block hides barrier drains. All ds reads/writes
// <=2-way bank aliased (free, m136).
__global__ __launch_bounds__(256, 2) void gemm_kernel(const float* __restrict__ A,
                                                      const __bf16* __restrict__ Bt,
                                                      __bf16* __restrict__ C) {
  __shared__ __attribute__((aligned(16))) __bf16 As[64 * 512];   // rows 1KB
  __shared__ __attribute__((aligned(16))) __bf16 Bs[2][128 * 32]; // rows 64B
  const int m0 = blockIdx.x * 64;
  const int t = threadIdx.x;
  const int wave = t >> 6, lane = t & 63;
  const int quad = lane >> 4, l16 = lane & 15;
  const int wn = wave * 32;  // wave-tile 64m x 32n

  // lane-invariant pieces of the B staging address
  const int bs_s0 = wave * 128 + lane;           // seg base for q=0 (q adds 64)
#define ISSUE_B(nt, kki, buf)                                                   \
  {                                                                             \
    _Pragma("unroll") for (int q = 0; q < 2; ++q) {                             \
      int s = bs_s0 + q * 64;                                                   \
      int n = s >> 2, cc = s & 3;                                               \
      int csw = cc ^ ((n >> 1) & 3);                                            \
      const __bf16* src = Bt + (size_t)((nt)*128 + n) * 512 + (kki)*32 + csw*8; \
      __builtin_amdgcn_global_load_lds(                                         \
          (const __attribute__((address_space(1))) void*)src,                   \
          (__attribute__((address_space(3))) void*)(&Bs[buf][0] +               \
                                                    (wave * 2 + q) * 512),      \
          16, 0, 0);                                                            \
    }                                                                           \
  }

  ISSUE_B(0, 0, 0);  // prefetch first B while staging A

  // A staging: coalesced float4 reads, bf16 convert, swizzled 8B LDS writes
#pragma unroll
  for (int j = 0; j < 32; ++j) {
    int f = j * 256 + t;  // float4 id within tile
    int m = f >> 7;
    int k = (f & 127) * 4;
    float4 v = *(const float4*)(A + (size_t)(m0 + m) * 512 + k);
    int c = k >> 3, half = (k >> 2) & 1;
    int csw = (c & ~7) | ((c & 7) ^ (m & 7));
    bf16x4 o = {(__bf16)v.x, (__bf16)v.y, (__bf16)v.z, (__bf16)v.w};
    *(bf16x4*)((char*)As + m * 1024 + csw * 16 + half * 8) = o;
  }
  __syncthreads();  // A ready + B(it=0) drained

  floatx4 acc[4][2] = {};

  for (int it = 0; it < 192; ++it) {
    const int buf = it & 1;
    if (it + 1 < 192) ISSUE_B((it + 1) >> 4, (it + 1) & 15, buf ^ 1);
    const int kki = it & 15;
    bf16x8 af[4];
    bf16x8 bfr[2];
#pragma unroll
    for (int tt = 0; tt < 4; ++tt) {
      int m = tt * 16 + l16;
      int c = kki * 4 + quad;
      int csw = (c & ~7) | ((c & 7) ^ (m & 7));
      af[tt] = *(const bf16x8*)((const char*)As + m * 1024 + csw * 16);
    }
#pragma unroll
    for (int tn = 0; tn < 2; ++tn) {
      int n = wn + tn * 16 + l16;
      int csw = quad ^ ((n >> 1) & 3);
      bfr[tn] = *(const bf16x8*)((const char*)&Bs[buf][0] + n * 64 + csw * 16);
    }
#pragma unroll
    for (int tm = 0; tm < 4; ++tm)
#pragma unroll
      for (int tn = 0; tn < 2; ++tn)
        acc[tm][tn] = __builtin_amdgcn_mfma_f32_16x16x32_bf16(
            af[tm], bfr[tn], acc[tm][tn], 0, 0, 0);
    if (kki == 15) {  // n-tile done: store u, reset acc
      int nt = it >> 4;
#pragma unroll
      for (int tm = 0; tm < 4; ++tm)
#pragma unroll
        for (int tn = 0; tn < 2; ++tn)
#pragma unroll
          for (int i = 0; i < 4; ++i) {
            int m = m0 + tm * 16 + quad * 4 + i;
            int n = nt * 128 + wn + tn * 16 + l16;
            C[(size_t)m * 1536 + n] = (__bf16)acc[tm][tn][i];
            acc[tm][tn][i] = 0.f;
          }
    }
    __syncthreads();
  }
#undef ISSUE_B
}

// ---- SRU scan: 2 alternating consumer waves + u/x producer waves -------------
// 256 blocks x 256 thr. Block g: b=g>>3, j=j0+lane (64 channels). Stages of 32
// steps; 2-deep LDS ring (u 12KB + x 8KB per stage). Consumers w0/w1 ping-pong
// stages, c handed off via LDS (halves per-wave issue pressure). Producers
// w2 (u) / w3 (x) prefetch stage s+1 via global_load_lds; the per-stage
// __syncthreads drains vmcnt -> data ready.
__global__ __launch_bounds__(256, 1) void scan_kernel(
    const __bf16* __restrict__ u, const float* __restrict__ x,
    const float* __restrict__ wc, const float* __restrict__ bias,
    const float* __restrict__ c0, float* __restrict__ out) {
  __shared__ __attribute__((aligned(16))) unsigned char ring[2][20480];
  __shared__ float cbuf[64];
  const int g = blockIdx.x;
  const int b = g >> 3;
  const int j0 = (g & 7) * 64;
  const int wid = threadIdx.x >> 6;
  const int lane = threadIdx.x & 63;

  if (wid == 2) {  // u producer: 12 KB/stage = 12 instrs
    int off_u[12];
#pragma unroll
    for (int r = 0; r < 12; ++r) {
      int q = r * 64 + lane;
      int tl = q / 24, rem = q - tl * 24;
      int gg = rem >> 3, sj = rem & 7;
      off_u[r] = tl * 49152 + b * 1536 + gg * 512 + j0 + sj * 8;
    }
#pragma unroll
    for (int r = 0; r < 12; ++r)
      __builtin_amdgcn_global_load_lds(
          (const __attribute__((address_space(1))) void*)(u + off_u[r]),
          (__attribute__((address_space(3))) void*)(ring[0] + r * 1024), 16, 0, 0);
    __syncthreads();
    for (int s = 0; s < 32; ++s) {
      if (s + 1 < 32) {
        const __bf16* ub = u + (size_t)(s + 1) * 32 * 49152;
        unsigned char* base = ring[(s + 1) & 1];
#pragma unroll
        for (int r = 0; r < 12; ++r)
          __builtin_amdgcn_global_load_lds(
              (const __attribute__((address_space(1))) void*)(ub + off_u[r]),
              (__attribute__((address_space(3))) void*)(base + r * 1024), 16, 0, 0);
      }
      __syncthreads();
    }
  } else if (wid == 3) {  // x producer: 8 KB/stage = 8 instrs
    int off_x[8];
#pragma unroll
    for (int r = 0; r < 8; ++r) {
      int p = r * 64 + lane;
      int tl = p >> 4, sj = p & 15;
      off_x[r] = tl * 16384 + b * 512 + j0 + sj * 4;
    }
#pragma unroll
    for (int r = 0; r < 8; ++r)
      __builtin_amdgcn_global_load_lds(
          (const __attribute__((address_space(1))) void*)(x + off_x[r]),
          (__attribute__((address_space(3))) void*)(ring[0] + 12288 + r * 1024),
          16, 0, 0);
    __syncthreads();
    for (int s = 0; s < 32; ++s) {
      if (s + 1 < 32) {
        const float* xb = x + (size_t)(s + 1) * 32 * 16384;
        unsigned char* base = ring[(s + 1) & 1];
#pragma unroll
        for (int r = 0; r < 8; ++r)
          __builtin_amdgcn_global_load_lds(
              (const __attribute__((address_space(1))) void*)(xb + off_x[r]),
              (__attribute__((address_space(3))) void*)(base + 12288 + r * 1024),
              16, 0, 0);
      }
      __syncthreads();
    }
  } else {  // consumers: wid 0 = even stages, wid 1 = odd stages
    const int j = j0 + lane;
    const int ob = b * 512 + j;
    const float vf = wc[j], vr = wc[512 + j];
    const float bfv = bias[j], brv = bias[512 + j];
    const float nvf = -vf * LOG2E, nvr = -vr * LOG2E;
    const float pbf = -bfv * LOG2E, pbr = -brv * LOG2E;
    const float n2 = -2.f * LOG2E;
    float c = c0[ob];
    __syncthreads();
    for (int s = 0; s < 32; ++s) {
      if ((s & 1) == wid) {
        if (s > 0) c = cbuf[lane];
        const unsigned char* base = ring[s & 1];
        float* op = out + (size_t)s * 32 * 16384 + ob;
#pragma unroll
        for (int i = 0; i < 32; ++i) {
          float u0 = (float)*(const __bf16*)(base + i * 384 + lane * 2);
          float u1 = (float)*(const __bf16*)(base + i * 384 + 128 + lane * 2);
          float u2 = (float)*(const __bf16*)(base + i * 384 + 256 + lane * 2);
          float xv = *(const float*)(base + 12288 + i * 256 + lane * 4);
          // f = sigmoid(u1 + vf*c + bf) via native exp2
          float a1 = __builtin_fmaf(nvf, c, __builtin_fmaf(u1, -LOG2E, pbf));
          float f = __builtin_amdgcn_rcpf(1.f + __builtin_exp2f(a1));
          c = __builtin_fmaf(f, c - u0, u0);
          float a2 = __builtin_fmaf(nvr, c, __builtin_fmaf(u2, -LOG2E, pbr));
          float r = __builtin_amdgcn_rcpf(1.f + __builtin_exp2f(a2));
          // tanh(c) = 2*sigmoid(2c) - 1
          float tg = __builtin_amdgcn_rcpf(1.f + __builtin_exp2f(c * n2));
          float gg = __builtin_fmaf(2.f, tg, -1.f);
          float xs = xv * 1.7320508075688772f;
          float h = __builtin_fmaf(r, gg - xs, xs);
          op[(size_t)i * 16384] = h;
        }
        if (s < 31) cbuf[lane] = c;
      }
      __syncthreads();
    }
    if (wid == 1) out[(size_t)16777216 + ob] = c;  // stage 31 owner holds c_last
  }
}

extern "C" void kernel_launch(void* const* d_in, const int* in_sizes, int n_in,
                              void* d_out, int out_size, void* d_ws, size_t ws_size,
                              hipStream_t stream) {
  const float* x = (const float*)d_in[0];     // (1024,32,512) fp32
  const float* w = (const float*)d_in[1];     // (512,1536)    fp32
  const float* wc = (const float*)d_in[2];    // (1024,)       fp32
  const float* bias = (const float*)d_in[3];  // (1024,)       fp32
  const float* c0 = (const float*)d_in[4];    // (32,512)      fp32
  float* out = (float*)d_out;                 // h (L,B,d) | c_last (B,d)

  char* ws = (char*)d_ws;
  __bf16* wt = (__bf16*)ws;             // 1,572,864 B
  __bf16* u = (__bf16*)(ws + 1572864);  // 100,663,296 B

  cvt_w<<<3072, 256, 0, stream>>>(w, wt);
  gemm_kernel<<<512, 256, 0, stream>>>(x, wt, u);
  scan_kernel<<<256, 256, 0, stream>>>(u, x, wc, bias, c0, out);
}